// Round 8
// baseline (114.710 us; speedup 1.0000x reference)
//
#include <hip/hip_runtime.h>

#define B_ 4
#define H_ 12
#define N_ 1028
#define D_ 64
#define R_ 4
#define L_ 3969
#define HID_ 32
#define KBLK 64
#define NT_ 17
#define NBH_ 48
#define QBLK 128
#define NQT 9              // ceil(1028/128)
#define KS_ 2              // k-split
#define NWG (NBH_*NQT*KS_) // 864 = 8*108
#define NROW (NBH_*N_)     // 49344
#define MUTP 1088
#define LOG2E 1.4426950408889634f
#define SCL1 (0.125f*LOG2E)

typedef __attribute__((ext_vector_type(8)))  short bf16x8;
typedef __attribute__((ext_vector_type(2)))  float f32x2;
typedef __attribute__((ext_vector_type(4)))  float f32x4;
typedef __attribute__((ext_vector_type(16))) float f32x16;
typedef __attribute__((ext_vector_type(2)))  unsigned int u32x2;
typedef __attribute__((ext_vector_type(4)))  unsigned int u32x4;

__device__ __forceinline__ unsigned pkbf(float lo, float hi) {
  unsigned r;
  asm("v_cvt_pk_bf16_f32 %0, %1, %2" : "=v"(r) : "v"(lo), "v"(hi));
  return r;
}
__device__ __forceinline__ float b2f(unsigned short u) {
  return __builtin_bit_cast(float, (unsigned)u << 16);
}
__device__ __forceinline__ float exp2_fast(float x) {
  float r; asm("v_exp_f32 %0, %1" : "=v"(r) : "v"(x)); return r;
}
__device__ __forceinline__ float sgnlog1p(float x) {
  float t = log1pf(fabsf(x));
  return (x > 0.f) ? t : ((x < 0.f) ? -t : 0.f);
}

// ---- fused prep: bt MLP -> bf16 table (blocks 0..15); mut = sgnlog1p(mu_k)*gscl ----
__global__ __launch_bounds__(256) void btmu_kernel(
    const float* __restrict__ rel, const float* __restrict__ W1,
    const float* __restrict__ b1, const float* __restrict__ W2,
    const float* __restrict__ gammag, const float* __restrict__ mug,
    unsigned short* __restrict__ btw, float* __restrict__ mut) {
  const int blk = blockIdx.x;
  const int tid = threadIdx.x;
  if (blk < 16) {
    int l = blk * 256 + tid;
    if (l >= L_) return;
    float r0 = rel[2*l], r1 = rel[2*l+1];
    float hid[HID_];
#pragma unroll
    for (int j = 0; j < HID_; ++j) {
      float x = W1[2*j]*r0 + W1[2*j+1]*r1 + b1[j];
      hid[j] = 0.5f * x * (1.f + erff(x * 0.70710678118654752f));
    }
#pragma unroll
    for (int h = 0; h < H_; ++h) {
      float acc = 0.f;
#pragma unroll
      for (int j = 0; j < HID_; ++j) acc += W2[h*HID_+j]*hid[j];
      btw[h*L_ + l] = (unsigned short)(pkbf(acc, acc) & 0xffffu);
    }
  } else {
    int idx = (blk - 16) * 256 + tid;            // over 48*1088 (padded)
    if (idx >= NBH_*MUTP) return;
    int bh = idx / MUTP, n = idx - bh*MUTP;
    int b = bh / H_, h = bh - b*H_;
    int nc = n < N_ ? n : N_-1;
    float gscl = LOG2E / (1.f + __expf(-gammag[h]));
    mut[idx] = sgnlog1p(mug[((size_t)b*2*H_ + H_ + h)*N_ + nc]) * gscl;
  }
}

// ---- flash attention, 32x32x16 MFMA, 4 waves x 32 q-rows, K-split x2 ----
// S^T = mfma(A=K, B=Q): D col=lane&31=q, row=(reg&3)+8(reg>>2)+4hi = kc (+32/blk).
// P in registers (k-slot map == D kc pattern); V^T staged kc-bits2<->3 swapped.
// O^T = mfma(A=V^T, B=P^T) -> softmax state lane-local. Partials to d_out/ws.
__global__ __launch_bounds__(256, 3) void attn_kernel(
    const float* __restrict__ qg, const float* __restrict__ kg_,
    const float* __restrict__ vg, const float* __restrict__ mug,
    const float* __restrict__ gammag, const unsigned short* __restrict__ btw,
    const float* __restrict__ mut, float* __restrict__ pO1,
    float* __restrict__ ml0, float* __restrict__ ml1, float* __restrict__ outg)
{
  __shared__ __align__(16) float btgs[L_ + 4];            // [0..3]=0 sentinel, gscl-folded
  __shared__ __align__(16) unsigned short Kl[2][64*64];   // [kc][d] bf16, granule^=(kc&7)
  __shared__ __align__(16) unsigned short Vl[2][64*64];   // V^T [d][kc'] (kc bits2<->3), gran^=(d&7)

  const int tid  = threadIdx.x;
  const int w    = tid >> 6;
  const int lane = tid & 63;
  const int hi   = lane >> 5;
  const int c    = lane & 31;

  // bijective XCD swizzle: 864 = 8 x 108; consecutive wg share bh (L2 locality)
  const int orig = blockIdx.x;
  const int wg   = (orig & 7) * (NWG/8) + (orig >> 3);
  const int bh   = wg / (NQT*KS_);
  const int rem  = wg - bh*(NQT*KS_);
  const int qt   = rem >> 1;
  const int ks   = rem & 1;
  const int b    = bh / H_;
  const int h    = bh - b * H_;
  const int q0   = qt * QBLK;
  const int tbeg = ks ? 9 : 0;
  const int tend = ks ? 17 : 9;

  const float gscl = LOG2E / (1.f + __expf(-gammag[h]));
  for (int i = tid; i < L_; i += 256) btgs[4 + i] = gscl * b2f(btw[h*L_ + i]);
  if (tid < 4) btgs[tid] = 0.f;

  const float* qb = qg  + (size_t)bh*N_*D_;
  const float* kb = kg_ + (size_t)bh*N_*D_;
  const float* vb = vg  + (size_t)bh*N_*D_;
  const float* mt = mut + bh*MUTP;

  // Q fragments: qf[m] = Q[qrow][16m+8hi .. +7] * SCL1
  const int qrow = q0 + 32*w + c;
  const int qrc  = qrow < N_ ? qrow : N_-1;
  bf16x8 qf[4];
#pragma unroll
  for (int m = 0; m < 4; ++m) {
    const float* p = qb + (size_t)qrc*D_ + 16*m + 8*hi;
    f32x4 a0 = *(const f32x4*)p;
    f32x4 a1 = *(const f32x4*)(p + 4);
    u32x4 qw;
    qw[0] = pkbf(a0[0]*SCL1, a0[1]*SCL1); qw[1] = pkbf(a0[2]*SCL1, a0[3]*SCL1);
    qw[2] = pkbf(a1[0]*SCL1, a1[1]*SCL1); qw[3] = pkbf(a1[2]*SCL1, a1[3]*SCL1);
    qf[m] = __builtin_bit_cast(bf16x8, qw);
  }
  const float muq_c = (qrow < N_) ? sgnlog1p(mug[((size_t)b*2*H_ + h)*N_ + qrow]) * gscl : 0.f;
  const int  qi  = qrow - R_;
  const bool qok = (qi >= 0) && (qrow < N_);
  const int  qy  = qi >> 5, qx = qi & 31;
  const int  lqc = qy*63 + qx + 1988;

  // staging roles (256 thr): K row=tid>>2, granule-pair=(tid&3)*2; V kc-quad x d-quad
  const int skr  = tid >> 2;
  const int sgp  = (tid & 3) * 2;
  const int vkc0 = (tid & 15) * 4;
  const int vd0  = (tid >> 4) * 4;
  const int vkc0p = ((vkc0 >> 1) & 4) | ((vkc0 << 1) & 8) | (vkc0 & 48); // bits2<->3

  f32x4 kpre[4], vpre[4];
  auto issue = [&](int tt) {
    const int k0n = tt * KBLK;
    {
      int kr = k0n + skr; if (kr >= N_) kr = N_-1;
      const float* p = kb + (size_t)kr*D_ + sgp*8;
      kpre[0] = *(const f32x4*)p;       kpre[1] = *(const f32x4*)(p + 4);
      kpre[2] = *(const f32x4*)(p + 8); kpre[3] = *(const f32x4*)(p + 12);
    }
#pragma unroll
    for (int i = 0; i < 4; ++i) {
      int kr = k0n + vkc0 + i; if (kr >= N_) kr = N_-1;
      vpre[i] = *(const f32x4*)(vb + (size_t)kr*D_ + vd0);
    }
  };

  float mrun = -3.0e38f, lrun = 0.f;
  f32x16 Ot[2];
#pragma unroll
  for (int blk = 0; blk < 2; ++blk)
#pragma unroll
    for (int r = 0; r < 16; ++r) Ot[blk][r] = 0.f;

  issue(tbeg);

  for (int t = tbeg; t < tend; ++t) {
    const int k0 = t * KBLK;
    const int p  = (t - tbeg) & 1;
    // ---- staged regs -> LDS buf p ----
    {
      const int sw = (skr & 7) << 3;
      u32x4 kw0, kw1;
      kw0[0] = pkbf(kpre[0][0], kpre[0][1]); kw0[1] = pkbf(kpre[0][2], kpre[0][3]);
      kw0[2] = pkbf(kpre[1][0], kpre[1][1]); kw0[3] = pkbf(kpre[1][2], kpre[1][3]);
      kw1[0] = pkbf(kpre[2][0], kpre[2][1]); kw1[1] = pkbf(kpre[2][2], kpre[2][3]);
      kw1[2] = pkbf(kpre[3][0], kpre[3][1]); kw1[3] = pkbf(kpre[3][2], kpre[3][3]);
      *(u32x4*)&Kl[p][skr*64 + ((sgp*8) ^ sw)]       = kw0;
      *(u32x4*)&Kl[p][skr*64 + (((sgp+1)*8) ^ sw)]   = kw1;
#pragma unroll
      for (int j = 0; j < 4; ++j) {
        int d = vd0 + j;
        u32x2 vw = (u32x2){pkbf(vpre[0][j], vpre[1][j]), pkbf(vpre[2][j], vpre[3][j])};
        *(u32x2*)&Vl[p][d*64 + (vkc0p ^ ((d & 7) << 3))] = vw;
      }
    }
    if (t + 1 < tend) issue(t + 1);    // next-tile loads fly across the barrier
    __syncthreads();

    // mu_k quads (mut is gscl-folded, padded to 1088 so tile 16 reads stay in-row)
    f32x4 mkv[2][4];
#pragma unroll
    for (int bb = 0; bb < 2; ++bb)
#pragma unroll
      for (int r2 = 0; r2 < 4; ++r2)
        mkv[bb][r2] = *(const f32x4*)&mt[k0 + 32*bb + 8*r2 + 4*hi];

    // ---- S^T ----
    f32x16 sc[2];
#pragma unroll
    for (int bb = 0; bb < 2; ++bb)
#pragma unroll
      for (int r = 0; r < 16; ++r) sc[bb][r] = 0.f;
    __builtin_amdgcn_s_setprio(1);
#pragma unroll
    for (int m = 0; m < 4; ++m) {
      int sw = (c & 7) << 3;
      bf16x8 ka0 = *(const bf16x8*)&Kl[p][c*64      + ((16*m + 8*hi) ^ sw)];
      bf16x8 ka1 = *(const bf16x8*)&Kl[p][(32+c)*64 + ((16*m + 8*hi) ^ sw)];
      sc[0] = __builtin_amdgcn_mfma_f32_32x32x16_bf16(ka0, qf[m], sc[0], 0, 0, 0);
      sc[1] = __builtin_amdgcn_mfma_f32_32x32x16_bf16(ka1, qf[m], sc[1], 0, 0, 0);
    }
    __builtin_amdgcn_s_setprio(0);

    // ---- bias + mask + row max ----
    float smax = -3.0e38f;
#pragma unroll
    for (int bb = 0; bb < 2; ++bb) {
#pragma unroll
      for (int r2 = 0; r2 < 4; ++r2) {
        const f32x4 mk = mkv[bb][r2];
        int base_kc = 32*bb + 8*r2 + 4*hi;
        int ki0 = k0 + base_kc - R_;
        int lk  = (ki0 >> 5)*63 + (ki0 & 31);
        int va  = lqc - lk;
        bool okq = ((unsigned)ki0 < 1024u) && qok;
        int basep = okq ? va : 3;
        f32x4 bv;
        bv[0] = btgs[basep-3]; bv[1] = btgs[basep-2];
        bv[2] = btgs[basep-1]; bv[3] = btgs[basep];
        bool maskq = (ki0 < 1024);
#pragma unroll
        for (int rr = 0; rr < 4; ++rr) {
          float val = sc[bb][4*r2+rr] + (muq_c + mk[rr]) * bv[3-rr];
          val = maskq ? val : -3.0e38f;
          sc[bb][4*r2+rr] = val;
          smax = fmaxf(smax, val);
        }
      }
    }
    smax = fmaxf(smax, __shfl_xor(smax, 32));

    if (__any(smax > mrun)) {
      float mnew = fmaxf(mrun, smax);
      float corr = exp2_fast(mrun - mnew);
      lrun *= corr;
#pragma unroll
      for (int blk = 0; blk < 2; ++blk)
#pragma unroll
        for (int r = 0; r < 16; ++r) Ot[blk][r] *= corr;
      mrun = mnew;
    }

    float psum = 0.f;
#pragma unroll
    for (int bb = 0; bb < 2; ++bb)
#pragma unroll
      for (int r = 0; r < 16; ++r) {
        float pv = exp2_fast(sc[bb][r] - mrun);
        sc[bb][r] = pv;
        psum += pv;
      }
    psum += __shfl_xor(psum, 32);
    lrun += psum;

    u32x4 pa[4];
#pragma unroll
    for (int mm = 0; mm < 4; ++mm) {
      int bb = mm >> 1, s = (mm & 1) * 8;
#pragma unroll
      for (int j = 0; j < 4; ++j)
        pa[mm][j] = pkbf(sc[bb][s + 2*j], sc[bb][s + 2*j + 1]);
    }

    __builtin_amdgcn_s_setprio(1);
#pragma unroll
    for (int mm = 0; mm < 4; ++mm) {
      bf16x8 pfr = __builtin_bit_cast(bf16x8, pa[mm]);
      int sw = (c & 7) << 3;
      bf16x8 va0 = *(const bf16x8*)&Vl[p][c*64      + ((16*mm + 8*hi) ^ sw)];
      bf16x8 va1 = *(const bf16x8*)&Vl[p][(32+c)*64 + ((16*mm + 8*hi) ^ sw)];
      Ot[0] = __builtin_amdgcn_mfma_f32_32x32x16_bf16(va0, pfr, Ot[0], 0, 0, 0);
      Ot[1] = __builtin_amdgcn_mfma_f32_32x32x16_bf16(va1, pfr, Ot[1], 0, 0, 0);
    }
    __builtin_amdgcn_s_setprio(0);
  }

  // ---- epilogue: UNNORMALIZED partial O + (m,l) ----
  const int qo = q0 + 32*w + c;
  if (qo < N_) {
    const int row = bh*N_ + qo;
    float* ob = (ks == 0 ? outg : pO1) + (size_t)row*64;
#pragma unroll
    for (int blk = 0; blk < 2; ++blk)
#pragma unroll
      for (int r2 = 0; r2 < 4; ++r2) {
        int dbase = 8*r2 + 4*hi + 32*blk;
        f32x4 ov;
#pragma unroll
        for (int rr = 0; rr < 4; ++rr) ov[rr] = Ot[blk][4*r2+rr];
        *(f32x4*)(ob + dbase) = ov;
      }
    if (hi == 0) {
      float* mlp_ = (ks == 0 ? ml0 : ml1) + (size_t)row*2;
      mlp_[0] = mrun; mlp_[1] = lrun;
    }
  }
}

// ---- combine the two K-halves ----
__global__ __launch_bounds__(256) void comb_kernel(
    const float* __restrict__ pO1, const float* __restrict__ ml0,
    const float* __restrict__ ml1, float* __restrict__ outg) {
  int idx = blockIdx.x*256 + threadIdx.x;       // over NROW*16 quads
  int row = idx >> 4;
  int d4  = (idx & 15) * 4;
  float m0 = ml0[(size_t)row*2], l0 = ml0[(size_t)row*2+1];
  float m1 = ml1[(size_t)row*2], l1 = ml1[(size_t)row*2+1];
  float M  = fmaxf(m0, m1);
  float w0 = exp2_fast(m0 - M), w1 = exp2_fast(m1 - M);
  float rl = 1.f / (l0*w0 + l1*w1);
  f32x4 o0 = *(const f32x4*)(outg + (size_t)row*64 + d4);
  f32x4 o1 = *(const f32x4*)(pO1  + (size_t)row*64 + d4);
  f32x4 of;
#pragma unroll
  for (int j = 0; j < 4; ++j) of[j] = (o0[j]*w0 + o1[j]*w1) * rl;
  *(f32x4*)(outg + (size_t)row*64 + d4) = of;
}

extern "C" void kernel_launch(void* const* d_in, const int* in_sizes, int n_in,
                              void* d_out, int out_size, void* d_ws, size_t ws_size,
                              hipStream_t stream) {
  const float* q     = (const float*)d_in[0];
  const float* k     = (const float*)d_in[1];
  const float* v     = (const float*)d_in[2];
  const float* mu    = (const float*)d_in[3];
  const float* rel   = (const float*)d_in[4];
  const float* W1    = (const float*)d_in[5];
  const float* b1    = (const float*)d_in[6];
  const float* W2    = (const float*)d_in[7];
  const float* gamma = (const float*)d_in[8];
  // d_in[9] idx_table unused: index computed analytically in-kernel.

  // ws layout (13,725,728 B total; proven ws_size >= 13.77 MB in round 6):
  char* wsb = (char*)d_ws;
  unsigned short* btw = (unsigned short*)wsb;          // 12*3969 bf16 = 95,256
  float* mut = (float*)(wsb + 95264);                  // 48*1088 f32  = 208,896
  float* ml0 = (float*)(wsb + 304160);                 // 49344*2 f32  = 394,752
  float* ml1 = (float*)(wsb + 698912);                 // 49344*2 f32  = 394,752
  float* pO1 = (float*)(wsb + 1093664);                // 49344*64 f32 = 12,632,064

  const int mutblocks = (NBH_*MUTP + 255) / 256;       // 204
  btmu_kernel<<<dim3(16 + mutblocks), dim3(256), 0, stream>>>(rel, W1, b1, W2, gamma, mu, btw, mut);
  attn_kernel<<<dim3(NWG), dim3(256), 0, stream>>>(q, k, v, mu, gamma, btw, mut,
                                                   pO1, ml0, ml1, (float*)d_out);
  comb_kernel<<<dim3(NROW*16/256), dim3(256), 0, stream>>>(pO1, ml0, ml1, (float*)d_out);
}